// Round 2
// baseline (323.560 us; speedup 1.0000x reference)
//
#include <hip/hip_runtime.h>

#define DEV_INLINE __device__ __forceinline__

// Problem constants
#define HH 256
#define WW 256
#define AA 64
#define DCC 1024
#define NS 512
#define NPADL 2048
#define PI_F 3.14159265358979323846f

// ws layout (float offsets)
#define H_OFF     0          // 2048
#define SINO_OFF  2048       // 65536
#define DIFF_OFF  67584      // 65536
#define XIN_OFF   133120     // 65536
#define WT2F_OFF  198656     // 9216
#define WT1B_OFF  207872     // 9216
#define BUFA_OFF  217088     // 2097152
#define BUFB_OFF  2314240    // 2097152

// ---------------------------------------------------------------------------
// Setup: ramp-filter impulse response h, diff = -sinogram, weight transposes
// h[n] = (1/2048) * [ (-1)^n + (1/512) * sum_{k=1}^{1023} k*cos(pi*k*n/1024) ]
// (k=1024 term is (-1)^n with weight 1, k=0 is 0; rfft/irfft symmetry folded)
// blocks 0..63: h (32 outputs x 8 k-chunks); 64..319: diff; 320..355: wT2f; 356..391: wT1b
// ---------------------------------------------------------------------------
__global__ __launch_bounds__(256) void setup_kernel(
    const float* __restrict__ sino_in, const float* __restrict__ w2f,
    const float* __restrict__ w1b, float* __restrict__ h,
    float* __restrict__ diff, float* __restrict__ wT2f, float* __restrict__ wT1b) {
  const int b = blockIdx.x;
  const int tid = threadIdx.x;
  if (b < 64) {
    __shared__ float hp[8][32];
    const int cell = tid & 31;
    const int kq = tid >> 5;
    const int n = b * 32 + cell;
    float ssum = 0.0f;
    const float ang_scale = PI_F / 1024.0f;
    for (int k = kq * 128; k < kq * 128 + 128; ++k) {
      int m = (k * n) & 2047;             // exact angle reduction mod 2*pi
      ssum += (float)k * cosf((float)m * ang_scale);
    }
    hp[kq][cell] = ssum;
    __syncthreads();
    if (tid < 32) {
      float S = 0.0f;
      #pragma unroll
      for (int q = 0; q < 8; ++q) S += hp[q][tid];
      int nn = b * 32 + tid;
      float sgn = (nn & 1) ? -1.0f : 1.0f;
      h[nn] = (S * (1.0f / 512.0f) + sgn) * (1.0f / 2048.0f);
    }
  } else if (b < 320) {
    int idx = (b - 64) * 256 + tid;       // < 65536
    diff[idx] = -sino_in[idx];
  } else if (b < 356) {
    int idx = (b - 320) * 256 + tid;      // < 9216
    int co = idx / 288;
    int r = idx - co * 288;               // r = ci*9 + j
    wT2f[r * 32 + co] = w2f[idx];
  } else {
    int idx = (b - 356) * 256 + tid;
    int co = idx / 288;
    int r = idx - co * 288;
    wT1b[r * 32 + co] = w1b[idx];
  }
}

// ---------------------------------------------------------------------------
// Fan-beam forward projection. grid 2048: a = b>>5, 32 detector cells/block,
// 8 sample-chunks of 64. Per-sample skip when outside image bounds.
// ---------------------------------------------------------------------------
__global__ __launch_bounds__(256) void fwdproj(
    const float* __restrict__ img, const float* __restrict__ theta,
    float* __restrict__ sino) {
  __shared__ float part[8][32];
  __shared__ float cs[2];
  const int tid = threadIdx.x;
  const int a = blockIdx.x >> 5;
  const int cell = tid & 31;
  const int chunk = tid >> 5;
  const int d = ((blockIdx.x & 31) << 5) + cell;
  if (tid == 0) {
    float th = theta[a];
    cs[0] = cosf(th);
    cs[1] = sinf(th);
  }
  __syncthreads();
  const float c = cs[0], s = cs[1];
  const float u = ((float)d - 511.5f) * 2.0f;
  const float dxv = -1000.0f * c - u * s;
  const float dyv = -1000.0f * s + u * c;
  const float L = sqrtf(1.0e6f + u * u);
  const float sx = fmaf(500.0f, c, 127.5f);  // src.x + image center
  const float sy = fmaf(500.0f, s, 127.5f);
  float acc = 0.0f;
  const int i0 = chunk << 6;
  for (int i = i0; i < i0 + 64; ++i) {
    float t = ((float)i + 0.5f) * (1.0f / 512.0f);
    float cx = fmaf(t, dxv, sx);
    float cy = fmaf(t, dyv, sy);
    if (cx <= -1.0f || cx >= 256.0f || cy <= -1.0f || cy >= 256.0f) continue;
    float xf = floorf(cx), yf = floorf(cy);
    float fx = cx - xf, fy = cy - yf;
    int ix = (int)xf, iy = (int)yf;            // in [-1,255]
    int ix0 = ix < 0 ? 0 : ix;
    int ix1 = ix >= 255 ? 255 : ix + 1;
    int iy0 = iy < 0 ? 0 : iy;
    int iy1 = iy >= 255 ? 255 : iy + 1;
    float mx0 = ix >= 0 ? 1.0f : 0.0f;
    float mx1 = ix < 255 ? 1.0f : 0.0f;
    float my0 = iy >= 0 ? 1.0f : 0.0f;
    float my1 = iy < 255 ? 1.0f : 0.0f;
    const float* r0 = img + (iy0 << 8);
    const float* r1 = img + (iy1 << 8);
    float v00 = r0[ix0] * (mx0 * my0);
    float v01 = r0[ix1] * (mx1 * my0);
    float v10 = r1[ix0] * (mx0 * my1);
    float v11 = r1[ix1] * (mx1 * my1);
    float gx = 1.0f - fx, gy = 1.0f - fy;
    acc += v00 * gx * gy + v01 * fx * gy + v10 * gx * fy + v11 * fx * fy;
  }
  part[chunk][cell] = acc;
  __syncthreads();
  if (tid < 32) {
    float r = 0.0f;
    #pragma unroll
    for (int q = 0; q < 8; ++q) r += part[q][tid];
    sino[a * 1024 + ((blockIdx.x & 31) << 5) + tid] = r * (L * (1.0f / 512.0f));
  }
}

// ---------------------------------------------------------------------------
// Ramp filter as direct circular conv: out[d] = sum_k s[k] * h[(d-k) mod 2048]
// grid 256: a = b>>2, k-chunk q = b&3 (256 k's). 4 outputs/thread.
// hext[n] = h[(n-2051)&2047] so the 7-float window per (4 out x 4 k) group is
// two aligned float4 reads. Partials atomicAdd'ed into diff (= -sinogram).
// ---------------------------------------------------------------------------
__global__ __launch_bounds__(256) void filt(
    const float* __restrict__ sino_pred, const float* __restrict__ h,
    float* __restrict__ diff) {
  __shared__ __align__(16) float srow[256];
  __shared__ __align__(16) float hext[4104];
  const int a = blockIdx.x >> 2;
  const int q = blockIdx.x & 3;
  const int tid = threadIdx.x;
  const int k0base = q * 256;
  srow[tid] = sino_pred[a * 1024 + k0base + tid];
  for (int n = tid; n < 4104; n += 256) hext[n] = h[(n - 2051) & 2047];
  __syncthreads();
  const int dd0 = tid * 4;
  float acc0 = 0.f, acc1 = 0.f, acc2 = 0.f, acc3 = 0.f;
  #pragma unroll 4
  for (int kk = 0; kk < 256; kk += 4) {
    float4 sv = *reinterpret_cast<const float4*>(&srow[kk]);
    int nb = dd0 + 2048 - k0base - kk;   // multiple of 4, in [772, 3072]
    float4 hA = *reinterpret_cast<const float4*>(&hext[nb]);
    float4 hB = *reinterpret_cast<const float4*>(&hext[nb + 4]);
    // out[dd0+o] needs h[dd0+o-(kk+j)] = hext[nb + o - j + 3] with layout shift
    acc0 = fmaf(sv.x, hA.w, acc0); acc0 = fmaf(sv.y, hA.z, acc0);
    acc0 = fmaf(sv.z, hA.y, acc0); acc0 = fmaf(sv.w, hA.x, acc0);
    acc1 = fmaf(sv.x, hB.x, acc1); acc1 = fmaf(sv.y, hA.w, acc1);
    acc1 = fmaf(sv.z, hA.z, acc1); acc1 = fmaf(sv.w, hA.y, acc1);
    acc2 = fmaf(sv.x, hB.y, acc2); acc2 = fmaf(sv.y, hB.x, acc2);
    acc2 = fmaf(sv.z, hA.w, acc2); acc2 = fmaf(sv.w, hA.z, acc2);
    acc3 = fmaf(sv.x, hB.z, acc3); acc3 = fmaf(sv.y, hB.y, acc3);
    acc3 = fmaf(sv.z, hB.x, acc3); acc3 = fmaf(sv.w, hA.w, acc3);
  }
  float* o = diff + a * 1024 + dd0;
  atomicAdd(o + 0, acc0);
  atomicAdd(o + 1, acc1);
  atomicAdd(o + 2, acc2);
  atomicAdd(o + 3, acc3);
}

// ---------------------------------------------------------------------------
// Pixel-driven backprojection fused with x_input = x - lambda * bp
// ---------------------------------------------------------------------------
__global__ __launch_bounds__(256) void backproj(
    const float* __restrict__ diff, const float* __restrict__ theta,
    const float* __restrict__ x, const float* __restrict__ lam_p,
    float* __restrict__ x_input) {
  __shared__ float cst[64], snt[64];
  const int tid = threadIdx.x;
  if (tid < 64) {
    float th = theta[tid];
    cst[tid] = cosf(th);
    snt[tid] = sinf(th);
  }
  __syncthreads();
  const int tX = (blockIdx.x & 3) << 6;
  const int tY = (blockIdx.x >> 2) << 2;
  const int pxi = tX + (tid & 63);
  const int pyi = tY + (tid >> 6);
  const float gx = (float)pxi - 127.5f;
  const float gy = (float)pyi - 127.5f;
  float acc = 0.0f;
  for (int a = 0; a < 64; ++a) {
    float c = cst[a], s = snt[a];
    float xr = gx * c + gy * s;
    float yr = gy * c - gx * s;
    float denom = 500.0f - xr;
    float inv = 1.0f / denom;
    float uu = yr * 1000.0f * inv;
    float wgt = 250000.0f * inv * inv;
    float iu = uu * 0.5f + 511.5f;
    float i0f = floorf(iu);
    float fr = iu - i0f;
    int i0 = (int)i0f;
    int c0 = min(max(i0, 0), 1023);
    int c1 = min(max(i0 + 1, 0), 1023);
    float m0 = (i0 >= 0 && i0 < 1024) ? 1.0f : 0.0f;
    float m1 = (i0 + 1 >= 0 && i0 + 1 < 1024) ? 1.0f : 0.0f;
    const float* row = diff + a * 1024;
    float v0 = row[c0] * m0;
    float v1 = row[c1] * m1;
    acc += (v0 * (1.0f - fr) + v1 * fr) * wgt;
  }
  float bp = acc * 0.04908738521234052f;  // pi/64
  int p = (pyi << 8) + pxi;
  x_input[p] = x[p] - lam_p[0] * bp;
}

// ---------------------------------------------------------------------------
// conv1_forward (1 -> 32) + relu. Tile 64x4, 1 px/thread, 32 couts in regs.
// ---------------------------------------------------------------------------
__global__ __launch_bounds__(256) void conv1fw(
    const float* __restrict__ in, const float* __restrict__ w,
    float* __restrict__ out) {
  __shared__ float tile[6][66];
  const int tid = threadIdx.x;
  const int tX = (blockIdx.x & 3) << 6;
  const int tY = (blockIdx.x >> 2) << 2;
  for (int idx = tid; idx < 396; idx += 256) {
    int yy = idx / 66;
    int xx = idx - yy * 66;
    int gy = tY + yy - 1, gxx = tX + xx - 1;
    tile[yy][xx] = (gy >= 0 && gy < 256 && gxx >= 0 && gxx < 256)
                       ? in[(gy << 8) + gxx] : 0.0f;
  }
  __syncthreads();
  const int px = tid & 63, py = tid >> 6;
  float v[9];
  #pragma unroll
  for (int dy = 0; dy < 3; ++dy)
    #pragma unroll
    for (int dx = 0; dx < 3; ++dx) v[dy * 3 + dx] = tile[py + dy][px + dx];
  const int p = ((tY + py) << 8) + tX + px;
  #pragma unroll
  for (int co = 0; co < 32; ++co) {
    float r = 0.0f;
    #pragma unroll
    for (int j = 0; j < 9; ++j) r = fmaf(v[j], w[co * 9 + j], r);
    out[(co << 16) + p] = fmaxf(r, 0.0f);
  }
}

// ---------------------------------------------------------------------------
// conv 32 -> 32. Tile 64x4 px, blockIdx.y selects 16-cout half.
// Optional soft-threshold on input (during LDS stage), optional relu on output.
// Weights wT[(ci*9+j)*32 + co] -> wave-uniform scalar-load stream.
// ---------------------------------------------------------------------------
template <bool SOFT, bool RELU>
__global__ __launch_bounds__(256) void conv32(
    const float* __restrict__ in, const float* __restrict__ wT,
    const float* __restrict__ thr_p, float* __restrict__ out) {
  __shared__ float tile[32][6][66];
  const int tid = threadIdx.x;
  const int tX = (blockIdx.x & 3) << 6;
  const int tY = (blockIdx.x >> 2) << 2;
  float thr = 0.0f;
  if (SOFT) thr = thr_p[0];
  for (int idx = tid; idx < 32 * 396; idx += 256) {
    int ci = idx / 396;
    int r = idx - ci * 396;
    int yy = r / 66;
    int xx = r - yy * 66;
    int gy = tY + yy - 1, gxx = tX + xx - 1;
    float v = 0.0f;
    if (gy >= 0 && gy < 256 && gxx >= 0 && gxx < 256)
      v = in[(ci << 16) + (gy << 8) + gxx];
    if (SOFT) {
      float av = fabsf(v) - thr;
      v = av > 0.0f ? (v < 0.0f ? -av : av) : 0.0f;
    }
    tile[ci][yy][xx] = v;
  }
  __syncthreads();
  const int px = tid & 63, py = tid >> 6;
  const int cbase = blockIdx.y * 16;
  float acc[16];
  #pragma unroll
  for (int i = 0; i < 16; ++i) acc[i] = 0.0f;
  for (int ci = 0; ci < 32; ++ci) {
    float v[9];
    #pragma unroll
    for (int dy = 0; dy < 3; ++dy)
      #pragma unroll
      for (int dx = 0; dx < 3; ++dx)
        v[dy * 3 + dx] = tile[ci][py + dy][px + dx];
    #pragma unroll
    for (int j = 0; j < 9; ++j) {
      const float* wrow = wT + (ci * 9 + j) * 32 + cbase;
      #pragma unroll
      for (int co = 0; co < 16; ++co) acc[co] = fmaf(v[j], wrow[co], acc[co]);
    }
  }
  const int p = ((tY + py) << 8) + tX + px;
  #pragma unroll
  for (int co = 0; co < 16; ++co) {
    float r = acc[co];
    if (RELU) r = fmaxf(r, 0.0f);
    out[((cbase + co) << 16) + p] = r;
  }
}

// ---------------------------------------------------------------------------
// conv2_backward (32 -> 1). MODE 0: out = conv. MODE 1: out = conv - x_input.
// ---------------------------------------------------------------------------
template <int MODE>
__global__ __launch_bounds__(256) void conv2bw(
    const float* __restrict__ in, const float* __restrict__ w,
    const float* __restrict__ x_input, float* __restrict__ out) {
  const int p = blockIdx.x * 256 + threadIdx.x;
  const int px = p & 255, py = p >> 8;
  float acc = 0.0f;
  for (int ci = 0; ci < 32; ++ci) {
    const float* base = in + (ci << 16);
    #pragma unroll
    for (int dy = 0; dy < 3; ++dy) {
      int gy = py + dy - 1;
      bool vy = (gy >= 0 && gy < 256);
      #pragma unroll
      for (int dx = 0; dx < 3; ++dx) {
        int gxx = px + dx - 1;
        float val = (vy && gxx >= 0 && gxx < 256) ? base[(gy << 8) + gxx] : 0.0f;
        acc = fmaf(val, w[ci * 9 + dy * 3 + dx], acc);
      }
    }
  }
  if (MODE == 0) out[p] = acc;
  else out[p] = acc - x_input[p];
}

extern "C" void kernel_launch(void* const* d_in, const int* in_sizes, int n_in,
                              void* d_out, int out_size, void* d_ws, size_t ws_size,
                              hipStream_t stream) {
  const float* x       = (const float*)d_in[0];
  const float* theta   = (const float*)d_in[1];
  const float* sino_in = (const float*)d_in[2];
  const float* lam     = (const float*)d_in[3];
  const float* thr     = (const float*)d_in[4];
  const float* w_c1f   = (const float*)d_in[5];
  const float* w_c2f   = (const float*)d_in[6];
  const float* w_c1b   = (const float*)d_in[7];
  const float* w_c2b   = (const float*)d_in[8];
  float* out = (float*)d_out;
  float* ws  = (float*)d_ws;

  float* h         = ws + H_OFF;
  float* sino_pred = ws + SINO_OFF;
  float* diff      = ws + DIFF_OFF;
  float* x_input   = ws + XIN_OFF;
  float* wT2f      = ws + WT2F_OFF;
  float* wT1b      = ws + WT1B_OFF;
  float* bufA      = ws + BUFA_OFF;
  float* bufB      = ws + BUFB_OFF;

  setup_kernel<<<392, 256, 0, stream>>>(sino_in, w_c2f, w_c1b, h, diff, wT2f, wT1b);
  fwdproj<<<2048, 256, 0, stream>>>(x, theta, sino_pred);
  filt<<<256, 256, 0, stream>>>(sino_pred, h, diff);
  backproj<<<256, 256, 0, stream>>>(diff, theta, x, lam, x_input);
  conv1fw<<<256, 256, 0, stream>>>(x_input, w_c1f, bufA);
  conv32<false, false><<<dim3(256, 2), 256, 0, stream>>>(bufA, wT2f, thr, bufB);
  conv32<true, true><<<dim3(256, 2), 256, 0, stream>>>(bufB, wT1b, thr, bufA);
  conv2bw<0><<<256, 256, 0, stream>>>(bufA, w_c2b, x_input, out);
  conv32<false, true><<<dim3(256, 2), 256, 0, stream>>>(bufB, wT1b, thr, bufA);
  conv2bw<1><<<256, 256, 0, stream>>>(bufA, w_c2b, x_input, out + 65536);
}

// Round 3
// 278.631 us; speedup vs baseline: 1.1613x; 1.1613x over previous
//
#include <hip/hip_runtime.h>

#define DEV_INLINE __device__ __forceinline__

// Problem constants
#define HH 256
#define WW 256
#define AA 64
#define DCC 1024
#define NS 512
#define NPADL 2048
#define PI_F 3.14159265358979323846f

// ws layout (float offsets)
#define H_OFF     0          // 2048
#define SINO_OFF  2048       // 65536
#define DIFF_OFF  67584      // 65536
#define XIN_OFF   133120     // 65536
#define WT2F_OFF  198656     // 9216
#define WT1B_OFF  207872     // 9216
#define BUFA_OFF  217088     // 2097152
#define BUFB_OFF  2314240    // 2097152
// quadP (258*258 float4 = 266256 floats) lives at BUFA_OFF: consumed by
// fwdproj, then bufA is overwritten by conv1fw later in the stream. 16B-aligned
// (217088*4 % 16 == 0).

// ---------------------------------------------------------------------------
// Setup: ramp-filter impulse response h, diff = -sinogram, weight transposes,
// and the bilinear quad-gather table quadP.
// h[n] = (1/2048) * [ (-1)^n + (1/512) * sum_{k=1}^{1023} k*cos(pi*k*n/1024) ]
// quadP[y][x] = (P(y,x), P(y,x+1), P(y+1,x), P(y+1,x+1)), y,x in [0,257],
//   P(a,b) = img[a-1][b-1] for a,b in [1,256], else 0.
// blocks: 0..63 h | 64..319 diff | 320..355 wT2f | 356..391 wT1b | 392..652 quadP
// ---------------------------------------------------------------------------
__global__ __launch_bounds__(256) void setup_kernel(
    const float* __restrict__ sino_in, const float* __restrict__ w2f,
    const float* __restrict__ w1b, const float* __restrict__ img,
    float* __restrict__ h, float* __restrict__ diff,
    float* __restrict__ wT2f, float* __restrict__ wT1b,
    float4* __restrict__ quadP) {
  const int b = blockIdx.x;
  const int tid = threadIdx.x;
  if (b < 64) {
    __shared__ float hp[8][32];
    const int cell = tid & 31;
    const int kq = tid >> 5;
    const int n = b * 32 + cell;
    float ssum = 0.0f;
    const float ang_scale = PI_F / 1024.0f;
    for (int k = kq * 128; k < kq * 128 + 128; ++k) {
      int m = (k * n) & 2047;             // exact angle reduction mod 2*pi
      ssum += (float)k * __cosf((float)m * ang_scale);
    }
    hp[kq][cell] = ssum;
    __syncthreads();
    if (tid < 32) {
      float S = 0.0f;
      #pragma unroll
      for (int q = 0; q < 8; ++q) S += hp[q][tid];
      int nn = b * 32 + tid;
      float sgn = (nn & 1) ? -1.0f : 1.0f;
      h[nn] = (S * (1.0f / 512.0f) + sgn) * (1.0f / 2048.0f);
    }
  } else if (b < 320) {
    int idx = (b - 64) * 256 + tid;       // < 65536
    diff[idx] = -sino_in[idx];
  } else if (b < 356) {
    int idx = (b - 320) * 256 + tid;      // < 9216
    int co = idx / 288;
    int r = idx - co * 288;               // r = ci*9 + j
    wT2f[r * 32 + co] = w2f[idx];
  } else if (b < 392) {
    int idx = (b - 356) * 256 + tid;
    int co = idx / 288;
    int r = idx - co * 288;
    wT1b[r * 32 + co] = w1b[idx];
  } else {
    int idx = (b - 392) * 256 + tid;
    if (idx < 258 * 258) {
      int y = idx / 258;
      int x = idx - y * 258;
      // P(a,b) with a=y..y+1, b=x..x+1
      float4 v;
      int ay = y - 1, by = x - 1;          // img coords for P(y,x)
      bool y0ok = (ay >= 0 && ay < 256);
      bool y1ok = (ay + 1 >= 0 && ay + 1 < 256);
      bool x0ok = (by >= 0 && by < 256);
      bool x1ok = (by + 1 >= 0 && by + 1 < 256);
      v.x = (y0ok && x0ok) ? img[(ay << 8) + by] : 0.0f;
      v.y = (y0ok && x1ok) ? img[(ay << 8) + by + 1] : 0.0f;
      v.z = (y1ok && x0ok) ? img[((ay + 1) << 8) + by] : 0.0f;
      v.w = (y1ok && x1ok) ? img[((ay + 1) << 8) + by + 1] : 0.0f;
      quadP[idx] = v;
    }
  }
}

// ---------------------------------------------------------------------------
// Fan-beam forward projection. grid 2048: a = b>>5, 32 detector cells/block,
// 8 chunk-threads/cell stride the analytically-clipped sample range.
// One float4 gather per bilinear sample (quadP table), branch-free body:
// cx,cy clamped to [-1,256] where padded-table contributions are exactly 0.
// ---------------------------------------------------------------------------
__global__ __launch_bounds__(256) void fwdproj(
    const float4* __restrict__ quadP, const float* __restrict__ theta,
    float* __restrict__ sino) {
  __shared__ float part[8][32];
  __shared__ float cs[2];
  const int tid = threadIdx.x;
  const int a = blockIdx.x >> 5;
  const int cell = tid & 31;
  const int chunk = tid >> 5;
  const int d = ((blockIdx.x & 31) << 5) + cell;
  if (tid == 0) {
    float th = theta[a];
    cs[0] = cosf(th);
    cs[1] = sinf(th);
  }
  __syncthreads();
  const float c = cs[0], s = cs[1];
  const float u = ((float)d - 511.5f) * 2.0f;
  const float dxv = -1000.0f * c - u * s;
  const float dyv = -1000.0f * s + u * c;
  const float L = sqrtf(1.0e6f + u * u);
  const float sx = fmaf(500.0f, c, 127.5f);  // src.x + image center
  const float sy = fmaf(500.0f, s, 127.5f);

  // Clip sample index range to the box [-1,256]^2 (with +-1 slack; safety via
  // coordinate clamp in the loop).
  float tlo = 0.0f, thi = 1.0f;
  if (fabsf(dxv) > 1e-6f) {
    float inv = 1.0f / dxv;
    float a0 = (-1.0f - sx) * inv, a1 = (256.0f - sx) * inv;
    tlo = fmaxf(tlo, fminf(a0, a1));
    thi = fminf(thi, fmaxf(a0, a1));
  } else if (sx <= -1.0f || sx >= 256.0f) {
    thi = -1.0f;
  }
  if (fabsf(dyv) > 1e-6f) {
    float inv = 1.0f / dyv;
    float a0 = (-1.0f - sy) * inv, a1 = (256.0f - sy) * inv;
    tlo = fmaxf(tlo, fminf(a0, a1));
    thi = fminf(thi, fmaxf(a0, a1));
  } else if (sy <= -1.0f || sy >= 256.0f) {
    thi = -1.0f;
  }
  int imin = (int)ceilf(tlo * 512.0f - 0.5f) - 1;
  imin = imin < 0 ? 0 : imin;
  int imax = (int)floorf(thi * 512.0f - 0.5f) + 1;
  imax = imax > 511 ? 511 : imax;

  float acc = 0.0f;
  for (int i = imin + chunk; i <= imax; i += 8) {
    float t = ((float)i + 0.5f) * (1.0f / 512.0f);
    float cx = fmaf(t, dxv, sx);
    float cy = fmaf(t, dyv, sy);
    cx = fminf(fmaxf(cx, -1.0f), 256.0f);
    cy = fminf(fmaxf(cy, -1.0f), 256.0f);
    float xf = floorf(cx), yf = floorf(cy);
    float fx = cx - xf, fy = cy - yf;
    int ix = (int)xf + 1;                  // [0, 257]
    int iy = (int)yf + 1;
    float4 q = quadP[iy * 258 + ix];
    float gx = 1.0f - fx, gy = 1.0f - fy;
    acc += gy * (gx * q.x + fx * q.y) + fy * (gx * q.z + fx * q.w);
  }
  part[chunk][cell] = acc;
  __syncthreads();
  if (tid < 32) {
    float r = 0.0f;
    #pragma unroll
    for (int q = 0; q < 8; ++q) r += part[q][tid];
    sino[a * 1024 + ((blockIdx.x & 31) << 5) + tid] = r * (L * (1.0f / 512.0f));
  }
}

// ---------------------------------------------------------------------------
// Ramp filter as direct circular conv: out[d] = sum_k s[k] * h[(d-k) mod 2048]
// grid 256: a = b>>2, k-chunk q = b&3 (256 k's). 4 outputs/thread.
// hext[n] = h[(n-2051)&2047] so the 7-float window per (4 out x 4 k) group is
// two aligned float4 reads. Partials atomicAdd'ed into diff (= -sinogram).
// ---------------------------------------------------------------------------
__global__ __launch_bounds__(256) void filt(
    const float* __restrict__ sino_pred, const float* __restrict__ h,
    float* __restrict__ diff) {
  __shared__ __align__(16) float srow[256];
  __shared__ __align__(16) float hext[4104];
  const int a = blockIdx.x >> 2;
  const int q = blockIdx.x & 3;
  const int tid = threadIdx.x;
  const int k0base = q * 256;
  srow[tid] = sino_pred[a * 1024 + k0base + tid];
  for (int n = tid; n < 4104; n += 256) hext[n] = h[(n - 2051) & 2047];
  __syncthreads();
  const int dd0 = tid * 4;
  float acc0 = 0.f, acc1 = 0.f, acc2 = 0.f, acc3 = 0.f;
  #pragma unroll 4
  for (int kk = 0; kk < 256; kk += 4) {
    float4 sv = *reinterpret_cast<const float4*>(&srow[kk]);
    int nb = dd0 + 2048 - k0base - kk;   // multiple of 4, in [772, 3072]
    float4 hA = *reinterpret_cast<const float4*>(&hext[nb]);
    float4 hB = *reinterpret_cast<const float4*>(&hext[nb + 4]);
    acc0 = fmaf(sv.x, hA.w, acc0); acc0 = fmaf(sv.y, hA.z, acc0);
    acc0 = fmaf(sv.z, hA.y, acc0); acc0 = fmaf(sv.w, hA.x, acc0);
    acc1 = fmaf(sv.x, hB.x, acc1); acc1 = fmaf(sv.y, hA.w, acc1);
    acc1 = fmaf(sv.z, hA.z, acc1); acc1 = fmaf(sv.w, hA.y, acc1);
    acc2 = fmaf(sv.x, hB.y, acc2); acc2 = fmaf(sv.y, hB.x, acc2);
    acc2 = fmaf(sv.z, hA.w, acc2); acc2 = fmaf(sv.w, hA.z, acc2);
    acc3 = fmaf(sv.x, hB.z, acc3); acc3 = fmaf(sv.y, hB.y, acc3);
    acc3 = fmaf(sv.z, hB.x, acc3); acc3 = fmaf(sv.w, hA.w, acc3);
  }
  float* o = diff + a * 1024 + dd0;
  atomicAdd(o + 0, acc0);
  atomicAdd(o + 1, acc1);
  atomicAdd(o + 2, acc2);
  atomicAdd(o + 3, acc3);
}

// ---------------------------------------------------------------------------
// Pixel-driven backprojection fused with x_input = x - lambda * bp
// ---------------------------------------------------------------------------
__global__ __launch_bounds__(256) void backproj(
    const float* __restrict__ diff, const float* __restrict__ theta,
    const float* __restrict__ x, const float* __restrict__ lam_p,
    float* __restrict__ x_input) {
  __shared__ float cst[64], snt[64];
  const int tid = threadIdx.x;
  if (tid < 64) {
    float th = theta[tid];
    cst[tid] = cosf(th);
    snt[tid] = sinf(th);
  }
  __syncthreads();
  const int tX = (blockIdx.x & 3) << 6;
  const int tY = (blockIdx.x >> 2) << 2;
  const int pxi = tX + (tid & 63);
  const int pyi = tY + (tid >> 6);
  const float gx = (float)pxi - 127.5f;
  const float gy = (float)pyi - 127.5f;
  float acc = 0.0f;
  for (int a = 0; a < 64; ++a) {
    float c = cst[a], s = snt[a];
    float xr = gx * c + gy * s;
    float yr = gy * c - gx * s;
    float denom = 500.0f - xr;
    float inv = 1.0f / denom;
    float uu = yr * 1000.0f * inv;
    float wgt = 250000.0f * inv * inv;
    float iu = uu * 0.5f + 511.5f;
    float i0f = floorf(iu);
    float fr = iu - i0f;
    int i0 = (int)i0f;
    int c0 = min(max(i0, 0), 1023);
    int c1 = min(max(i0 + 1, 0), 1023);
    float m0 = (i0 >= 0 && i0 < 1024) ? 1.0f : 0.0f;
    float m1 = (i0 + 1 >= 0 && i0 + 1 < 1024) ? 1.0f : 0.0f;
    const float* row = diff + a * 1024;
    float v0 = row[c0] * m0;
    float v1 = row[c1] * m1;
    acc += (v0 * (1.0f - fr) + v1 * fr) * wgt;
  }
  float bp = acc * 0.04908738521234052f;  // pi/64
  int p = (pyi << 8) + pxi;
  x_input[p] = x[p] - lam_p[0] * bp;
}

// ---------------------------------------------------------------------------
// conv1_forward (1 -> 32) + relu. Tile 64x4, 1 px/thread, 32 couts in regs.
// ---------------------------------------------------------------------------
__global__ __launch_bounds__(256) void conv1fw(
    const float* __restrict__ in, const float* __restrict__ w,
    float* __restrict__ out) {
  __shared__ float tile[6][66];
  const int tid = threadIdx.x;
  const int tX = (blockIdx.x & 3) << 6;
  const int tY = (blockIdx.x >> 2) << 2;
  for (int idx = tid; idx < 396; idx += 256) {
    int yy = idx / 66;
    int xx = idx - yy * 66;
    int gy = tY + yy - 1, gxx = tX + xx - 1;
    tile[yy][xx] = (gy >= 0 && gy < 256 && gxx >= 0 && gxx < 256)
                       ? in[(gy << 8) + gxx] : 0.0f;
  }
  __syncthreads();
  const int px = tid & 63, py = tid >> 6;
  float v[9];
  #pragma unroll
  for (int dy = 0; dy < 3; ++dy)
    #pragma unroll
    for (int dx = 0; dx < 3; ++dx) v[dy * 3 + dx] = tile[py + dy][px + dx];
  const int p = ((tY + py) << 8) + tX + px;
  #pragma unroll
  for (int co = 0; co < 32; ++co) {
    float r = 0.0f;
    #pragma unroll
    for (int j = 0; j < 9; ++j) r = fmaf(v[j], w[co * 9 + j], r);
    out[(co << 16) + p] = fmaxf(r, 0.0f);
  }
}

// ---------------------------------------------------------------------------
// conv 32 -> 32. Tile 64x4 px, blockIdx.y selects 16-cout half.
// Optional soft-threshold on input (during LDS stage), optional relu on output.
// Weights wT[(ci*9+j)*32 + co] -> wave-uniform scalar-load stream.
// ---------------------------------------------------------------------------
template <bool SOFT, bool RELU>
__global__ __launch_bounds__(256) void conv32(
    const float* __restrict__ in, const float* __restrict__ wT,
    const float* __restrict__ thr_p, float* __restrict__ out) {
  __shared__ float tile[32][6][66];
  const int tid = threadIdx.x;
  const int tX = (blockIdx.x & 3) << 6;
  const int tY = (blockIdx.x >> 2) << 2;
  float thr = 0.0f;
  if (SOFT) thr = thr_p[0];
  for (int idx = tid; idx < 32 * 396; idx += 256) {
    int ci = idx / 396;
    int r = idx - ci * 396;
    int yy = r / 66;
    int xx = r - yy * 66;
    int gy = tY + yy - 1, gxx = tX + xx - 1;
    float v = 0.0f;
    if (gy >= 0 && gy < 256 && gxx >= 0 && gxx < 256)
      v = in[(ci << 16) + (gy << 8) + gxx];
    if (SOFT) {
      float av = fabsf(v) - thr;
      v = av > 0.0f ? (v < 0.0f ? -av : av) : 0.0f;
    }
    tile[ci][yy][xx] = v;
  }
  __syncthreads();
  const int px = tid & 63, py = tid >> 6;
  const int cbase = blockIdx.y * 16;
  float acc[16];
  #pragma unroll
  for (int i = 0; i < 16; ++i) acc[i] = 0.0f;
  for (int ci = 0; ci < 32; ++ci) {
    float v[9];
    #pragma unroll
    for (int dy = 0; dy < 3; ++dy)
      #pragma unroll
      for (int dx = 0; dx < 3; ++dx)
        v[dy * 3 + dx] = tile[ci][py + dy][px + dx];
    #pragma unroll
    for (int j = 0; j < 9; ++j) {
      const float* wrow = wT + (ci * 9 + j) * 32 + cbase;
      #pragma unroll
      for (int co = 0; co < 16; ++co) acc[co] = fmaf(v[j], wrow[co], acc[co]);
    }
  }
  const int p = ((tY + py) << 8) + tX + px;
  #pragma unroll
  for (int co = 0; co < 16; ++co) {
    float r = acc[co];
    if (RELU) r = fmaxf(r, 0.0f);
    out[((cbase + co) << 16) + p] = r;
  }
}

// ---------------------------------------------------------------------------
// conv2_backward (32 -> 1). MODE 0: out = conv. MODE 1: out = conv - x_input.
// ---------------------------------------------------------------------------
template <int MODE>
__global__ __launch_bounds__(256) void conv2bw(
    const float* __restrict__ in, const float* __restrict__ w,
    const float* __restrict__ x_input, float* __restrict__ out) {
  const int p = blockIdx.x * 256 + threadIdx.x;
  const int px = p & 255, py = p >> 8;
  float acc = 0.0f;
  for (int ci = 0; ci < 32; ++ci) {
    const float* base = in + (ci << 16);
    #pragma unroll
    for (int dy = 0; dy < 3; ++dy) {
      int gy = py + dy - 1;
      bool vy = (gy >= 0 && gy < 256);
      #pragma unroll
      for (int dx = 0; dx < 3; ++dx) {
        int gxx = px + dx - 1;
        float val = (vy && gxx >= 0 && gxx < 256) ? base[(gy << 8) + gxx] : 0.0f;
        acc = fmaf(val, w[ci * 9 + dy * 3 + dx], acc);
      }
    }
  }
  if (MODE == 0) out[p] = acc;
  else out[p] = acc - x_input[p];
}

extern "C" void kernel_launch(void* const* d_in, const int* in_sizes, int n_in,
                              void* d_out, int out_size, void* d_ws, size_t ws_size,
                              hipStream_t stream) {
  const float* x       = (const float*)d_in[0];
  const float* theta   = (const float*)d_in[1];
  const float* sino_in = (const float*)d_in[2];
  const float* lam     = (const float*)d_in[3];
  const float* thr     = (const float*)d_in[4];
  const float* w_c1f   = (const float*)d_in[5];
  const float* w_c2f   = (const float*)d_in[6];
  const float* w_c1b   = (const float*)d_in[7];
  const float* w_c2b   = (const float*)d_in[8];
  float* out = (float*)d_out;
  float* ws  = (float*)d_ws;

  float* h         = ws + H_OFF;
  float* sino_pred = ws + SINO_OFF;
  float* diff      = ws + DIFF_OFF;
  float* x_input   = ws + XIN_OFF;
  float* wT2f      = ws + WT2F_OFF;
  float* wT1b      = ws + WT1B_OFF;
  float* bufA      = ws + BUFA_OFF;
  float* bufB      = ws + BUFB_OFF;
  float4* quadP    = (float4*)(ws + BUFA_OFF);   // dead once fwdproj completes

  setup_kernel<<<653, 256, 0, stream>>>(sino_in, w_c2f, w_c1b, x, h, diff,
                                        wT2f, wT1b, quadP);
  fwdproj<<<2048, 256, 0, stream>>>(quadP, theta, sino_pred);
  filt<<<256, 256, 0, stream>>>(sino_pred, h, diff);
  backproj<<<256, 256, 0, stream>>>(diff, theta, x, lam, x_input);
  conv1fw<<<256, 256, 0, stream>>>(x_input, w_c1f, bufA);
  conv32<false, false><<<dim3(256, 2), 256, 0, stream>>>(bufA, wT2f, thr, bufB);
  conv32<true, true><<<dim3(256, 2), 256, 0, stream>>>(bufB, wT1b, thr, bufA);
  conv2bw<0><<<256, 256, 0, stream>>>(bufA, w_c2b, x_input, out);
  conv32<false, true><<<dim3(256, 2), 256, 0, stream>>>(bufB, wT1b, thr, bufA);
  conv2bw<1><<<256, 256, 0, stream>>>(bufA, w_c2b, x_input, out + 65536);
}

// Round 5
// 273.392 us; speedup vs baseline: 1.1835x; 1.0192x over previous
//
#include <hip/hip_runtime.h>

#define DEV_INLINE __device__ __forceinline__

// Problem constants
#define HH 256
#define WW 256
#define AA 64
#define DCC 1024
#define NS 512
#define NPADL 2048
#define PI_F 3.14159265358979323846f

// ws layout (float offsets)
#define H_OFF     0          // 2048
#define SINO_OFF  2048       // 65536
#define DIFF_OFF  67584      // 65536
#define XIN_OFF   133120     // 65536
#define WT2F_OFF  198656     // 9216
#define WT1B_OFF  207872     // 9216
#define BUFA_OFF  217088     // 2097152
#define BUFB_OFF  2314240    // 2097152
#define BUFC_OFF  4411392    // 2097152
// quadP (258*258 float4) lives at BUFA_OFF: consumed by fwdproj, then bufA is
// reused by conv1b_dual later in the stream. 16B-aligned.

// ---------------------------------------------------------------------------
// Setup: ramp-filter h, diff = -sinogram, weight transposes, quadP table,
// x_input = x (backproj partials atomicAdd into it).
// h[n] = (1/2048) * [ (-1)^n + (1/512) * sum_{k=1}^{1023} k*cos(pi*k*n/1024) ]
// blocks: 0..63 h | 64..319 diff | 320..355 wT2f | 356..391 wT1b |
//         392..652 quadP | 653..908 x_input=x
// ---------------------------------------------------------------------------
__global__ __launch_bounds__(256) void setup_kernel(
    const float* __restrict__ sino_in, const float* __restrict__ w2f,
    const float* __restrict__ w1b, const float* __restrict__ img,
    float* __restrict__ h, float* __restrict__ diff,
    float* __restrict__ wT2f, float* __restrict__ wT1b,
    float4* __restrict__ quadP, float* __restrict__ x_input) {
  const int b = blockIdx.x;
  const int tid = threadIdx.x;
  if (b < 64) {
    __shared__ float hp[8][32];
    const int cell = tid & 31;
    const int kq = tid >> 5;
    const int n = b * 32 + cell;
    float ssum = 0.0f;
    const float ang_scale = PI_F / 1024.0f;
    for (int k = kq * 128; k < kq * 128 + 128; ++k) {
      int m = (k * n) & 2047;             // exact angle reduction mod 2*pi
      ssum += (float)k * __cosf((float)m * ang_scale);
    }
    hp[kq][cell] = ssum;
    __syncthreads();
    if (tid < 32) {
      float S = 0.0f;
      #pragma unroll
      for (int q = 0; q < 8; ++q) S += hp[q][tid];
      int nn = b * 32 + tid;
      float sgn = (nn & 1) ? -1.0f : 1.0f;
      h[nn] = (S * (1.0f / 512.0f) + sgn) * (1.0f / 2048.0f);
    }
  } else if (b < 320) {
    int idx = (b - 64) * 256 + tid;       // < 65536
    diff[idx] = -sino_in[idx];
  } else if (b < 356) {
    int idx = (b - 320) * 256 + tid;      // < 9216
    int co = idx / 288;
    int r = idx - co * 288;               // r = ci*9 + j
    wT2f[r * 32 + co] = w2f[idx];
  } else if (b < 392) {
    int idx = (b - 356) * 256 + tid;
    int co = idx / 288;
    int r = idx - co * 288;
    wT1b[r * 32 + co] = w1b[idx];
  } else if (b < 653) {
    int idx = (b - 392) * 256 + tid;
    if (idx < 258 * 258) {
      int y = idx / 258;
      int x = idx - y * 258;
      float4 v;
      int ay = y - 1, bx = x - 1;          // img coords for P(y,x)
      bool y0ok = (ay >= 0 && ay < 256);
      bool y1ok = (ay + 1 >= 0 && ay + 1 < 256);
      bool x0ok = (bx >= 0 && bx < 256);
      bool x1ok = (bx + 1 >= 0 && bx + 1 < 256);
      v.x = (y0ok && x0ok) ? img[(ay << 8) + bx] : 0.0f;
      v.y = (y0ok && x1ok) ? img[(ay << 8) + bx + 1] : 0.0f;
      v.z = (y1ok && x0ok) ? img[((ay + 1) << 8) + bx] : 0.0f;
      v.w = (y1ok && x1ok) ? img[((ay + 1) << 8) + bx + 1] : 0.0f;
      quadP[idx] = v;
    }
  } else {
    int idx = (b - 653) * 256 + tid;      // < 65536
    x_input[idx] = img[idx];
  }
}

// ---------------------------------------------------------------------------
// Fan-beam forward projection. grid 2048: a = b>>5, 32 detector cells/block,
// 8 chunk-threads/cell stride the analytically-clipped sample range.
// One float4 gather per bilinear sample (quadP table), branch-free body.
// ---------------------------------------------------------------------------
__global__ __launch_bounds__(256) void fwdproj(
    const float4* __restrict__ quadP, const float* __restrict__ theta,
    float* __restrict__ sino) {
  __shared__ float part[8][32];
  __shared__ float cs[2];
  const int tid = threadIdx.x;
  const int a = blockIdx.x >> 5;
  const int cell = tid & 31;
  const int chunk = tid >> 5;
  const int d = ((blockIdx.x & 31) << 5) + cell;
  if (tid == 0) {
    float th = theta[a];
    cs[0] = cosf(th);
    cs[1] = sinf(th);
  }
  __syncthreads();
  const float c = cs[0], s = cs[1];
  const float u = ((float)d - 511.5f) * 2.0f;
  const float dxv = -1000.0f * c - u * s;
  const float dyv = -1000.0f * s + u * c;
  const float L = sqrtf(1.0e6f + u * u);
  const float sx = fmaf(500.0f, c, 127.5f);
  const float sy = fmaf(500.0f, s, 127.5f);

  float tlo = 0.0f, thi = 1.0f;
  if (fabsf(dxv) > 1e-6f) {
    float inv = 1.0f / dxv;
    float a0 = (-1.0f - sx) * inv, a1 = (256.0f - sx) * inv;
    tlo = fmaxf(tlo, fminf(a0, a1));
    thi = fminf(thi, fmaxf(a0, a1));
  } else if (sx <= -1.0f || sx >= 256.0f) {
    thi = -1.0f;
  }
  if (fabsf(dyv) > 1e-6f) {
    float inv = 1.0f / dyv;
    float a0 = (-1.0f - sy) * inv, a1 = (256.0f - sy) * inv;
    tlo = fmaxf(tlo, fminf(a0, a1));
    thi = fminf(thi, fmaxf(a0, a1));
  } else if (sy <= -1.0f || sy >= 256.0f) {
    thi = -1.0f;
  }
  int imin = (int)ceilf(tlo * 512.0f - 0.5f) - 1;
  imin = imin < 0 ? 0 : imin;
  int imax = (int)floorf(thi * 512.0f - 0.5f) + 1;
  imax = imax > 511 ? 511 : imax;

  float acc = 0.0f;
  for (int i = imin + chunk; i <= imax; i += 8) {
    float t = ((float)i + 0.5f) * (1.0f / 512.0f);
    float cx = fmaf(t, dxv, sx);
    float cy = fmaf(t, dyv, sy);
    cx = fminf(fmaxf(cx, -1.0f), 256.0f);
    cy = fminf(fmaxf(cy, -1.0f), 256.0f);
    float xf = floorf(cx), yf = floorf(cy);
    float fx = cx - xf, fy = cy - yf;
    int ix = (int)xf + 1;
    int iy = (int)yf + 1;
    float4 q = quadP[iy * 258 + ix];
    float gx = 1.0f - fx, gy = 1.0f - fy;
    acc += gy * (gx * q.x + fx * q.y) + fy * (gx * q.z + fx * q.w);
  }
  part[chunk][cell] = acc;
  __syncthreads();
  if (tid < 32) {
    float r = 0.0f;
    #pragma unroll
    for (int q = 0; q < 8; ++q) r += part[q][tid];
    sino[a * 1024 + ((blockIdx.x & 31) << 5) + tid] = r * (L * (1.0f / 512.0f));
  }
}

// ---------------------------------------------------------------------------
// Ramp filter as direct circular conv, atomicAdd into diff (= -sinogram).
// ---------------------------------------------------------------------------
__global__ __launch_bounds__(256) void filt(
    const float* __restrict__ sino_pred, const float* __restrict__ h,
    float* __restrict__ diff) {
  __shared__ __align__(16) float srow[256];
  __shared__ __align__(16) float hext[4104];
  const int a = blockIdx.x >> 2;
  const int q = blockIdx.x & 3;
  const int tid = threadIdx.x;
  const int k0base = q * 256;
  srow[tid] = sino_pred[a * 1024 + k0base + tid];
  for (int n = tid; n < 4104; n += 256) hext[n] = h[(n - 2051) & 2047];
  __syncthreads();
  const int dd0 = tid * 4;
  float acc0 = 0.f, acc1 = 0.f, acc2 = 0.f, acc3 = 0.f;
  #pragma unroll 4
  for (int kk = 0; kk < 256; kk += 4) {
    float4 sv = *reinterpret_cast<const float4*>(&srow[kk]);
    int nb = dd0 + 2048 - k0base - kk;
    float4 hA = *reinterpret_cast<const float4*>(&hext[nb]);
    float4 hB = *reinterpret_cast<const float4*>(&hext[nb + 4]);
    acc0 = fmaf(sv.x, hA.w, acc0); acc0 = fmaf(sv.y, hA.z, acc0);
    acc0 = fmaf(sv.z, hA.y, acc0); acc0 = fmaf(sv.w, hA.x, acc0);
    acc1 = fmaf(sv.x, hB.x, acc1); acc1 = fmaf(sv.y, hA.w, acc1);
    acc1 = fmaf(sv.z, hA.z, acc1); acc1 = fmaf(sv.w, hA.y, acc1);
    acc2 = fmaf(sv.x, hB.y, acc2); acc2 = fmaf(sv.y, hB.x, acc2);
    acc2 = fmaf(sv.z, hA.w, acc2); acc2 = fmaf(sv.w, hA.z, acc2);
    acc3 = fmaf(sv.x, hB.z, acc3); acc3 = fmaf(sv.y, hB.y, acc3);
    acc3 = fmaf(sv.z, hB.x, acc3); acc3 = fmaf(sv.w, hA.w, acc3);
  }
  float* o = diff + a * 1024 + dd0;
  atomicAdd(o + 0, acc0);
  atomicAdd(o + 1, acc1);
  atomicAdd(o + 2, acc2);
  atomicAdd(o + 3, acc3);
}

// ---------------------------------------------------------------------------
// Pixel-driven backprojection, angle-split x4 for occupancy.
// x_input (pre-initialized to x) -= lam * pi/64 * partial via atomicAdd.
// ---------------------------------------------------------------------------
__global__ __launch_bounds__(256) void backproj_part(
    const float* __restrict__ diff, const float* __restrict__ theta,
    const float* __restrict__ lam_p, float* __restrict__ x_input) {
  __shared__ float cst[16], snt[16];
  const int tid = threadIdx.x;
  const int tileb = blockIdx.x & 255;
  const int a0 = (blockIdx.x >> 8) << 4;    // 0,16,32,48
  if (tid < 16) {
    float th = theta[a0 + tid];
    cst[tid] = cosf(th);
    snt[tid] = sinf(th);
  }
  __syncthreads();
  const int tX = (tileb & 3) << 6;
  const int tY = (tileb >> 2) << 2;
  const int pxi = tX + (tid & 63);
  const int pyi = tY + (tid >> 6);
  const float gx = (float)pxi - 127.5f;
  const float gy = (float)pyi - 127.5f;
  float acc = 0.0f;
  for (int ai = 0; ai < 16; ++ai) {
    float c = cst[ai], s = snt[ai];
    float xr = gx * c + gy * s;
    float yr = gy * c - gx * s;
    float denom = 500.0f - xr;
    float inv = 1.0f / denom;
    float uu = yr * 1000.0f * inv;
    float wgt = 250000.0f * inv * inv;
    float iu = uu * 0.5f + 511.5f;
    float i0f = floorf(iu);
    float fr = iu - i0f;
    int i0 = (int)i0f;
    int c0 = min(max(i0, 0), 1023);
    int c1 = min(max(i0 + 1, 0), 1023);
    float m0 = (i0 >= 0 && i0 < 1024) ? 1.0f : 0.0f;
    float m1 = (i0 + 1 >= 0 && i0 + 1 < 1024) ? 1.0f : 0.0f;
    const float* row = diff + (a0 + ai) * 1024;
    float v0 = row[c0] * m0;
    float v1 = row[c1] * m1;
    acc += (v0 * (1.0f - fr) + v1 * fr) * wgt;
  }
  int p = (pyi << 8) + pxi;
  atomicAdd(x_input + p, -lam_p[0] * 0.04908738521234052f * acc);
}

// ---------------------------------------------------------------------------
// Fused conv1_forward + relu + conv2_forward. Tile 64x4 out px.
// Phase 1: h(32ch) on 66x6 halo grid from x_input 68x8 tile -> LDS.
//          Halo positions OUTSIDE the image get h=0 (conv2's zero padding)!
// Phase 2: conv2f, all 32 couts in regs, -> x_forward.
// ---------------------------------------------------------------------------
__global__ __launch_bounds__(256) void conv12f(
    const float* __restrict__ x_input, const float* __restrict__ w1f,
    const float* __restrict__ wT2f, float* __restrict__ x_forward) {
  __shared__ float xin[8][68];
  __shared__ float htile[32][6][66];
  const int tid = threadIdx.x;
  const int tX = (blockIdx.x & 3) << 6;
  const int tY = (blockIdx.x >> 2) << 2;
  for (int idx = tid; idx < 544; idx += 256) {
    int r = idx / 68;
    int cc = idx - r * 68;
    int gy = tY + r - 2, gxx = tX + cc - 2;
    xin[r][cc] = (gy >= 0 && gy < 256 && gxx >= 0 && gxx < 256)
                     ? x_input[(gy << 8) + gxx] : 0.0f;
  }
  __syncthreads();
  for (int pos = tid; pos < 396; pos += 256) {
    int yy = pos / 66;
    int xx = pos - yy * 66;
    int hy = tY + yy - 1, hx = tX + xx - 1;       // h's global position
    bool hin = (hy >= 0 && hy < 256 && hx >= 0 && hx < 256);
    float v[9];
    #pragma unroll
    for (int dy = 0; dy < 3; ++dy)
      #pragma unroll
      for (int dx = 0; dx < 3; ++dx) v[dy * 3 + dx] = xin[yy + dy][xx + dx];
    #pragma unroll
    for (int co = 0; co < 32; ++co) {
      float r = 0.0f;
      #pragma unroll
      for (int j = 0; j < 9; ++j) r = fmaf(v[j], w1f[co * 9 + j], r);
      htile[co][yy][xx] = hin ? fmaxf(r, 0.0f) : 0.0f;
    }
  }
  __syncthreads();
  const int px = tid & 63, py = tid >> 6;
  float acc[32];
  #pragma unroll
  for (int i = 0; i < 32; ++i) acc[i] = 0.0f;
  for (int ci = 0; ci < 32; ++ci) {
    float v[9];
    #pragma unroll
    for (int dy = 0; dy < 3; ++dy)
      #pragma unroll
      for (int dx = 0; dx < 3; ++dx)
        v[dy * 3 + dx] = htile[ci][py + dy][px + dx];
    #pragma unroll
    for (int j = 0; j < 9; ++j) {
      const float* wrow = wT2f + (ci * 9 + j) * 32;
      #pragma unroll
      for (int co = 0; co < 32; ++co) acc[co] = fmaf(v[j], wrow[co], acc[co]);
    }
  }
  const int p = ((tY + py) << 8) + tX + px;
  #pragma unroll
  for (int co = 0; co < 32; ++co) x_forward[(co << 16) + p] = acc[co];
}

// ---------------------------------------------------------------------------
// Dual conv1_backward (+relu): branch 0 input = soft(x_forward) -> bufA,
// branch 1 input = x_forward -> bufC. grid 1024 = branch(2) x half(2) x tile(256).
// ---------------------------------------------------------------------------
__global__ __launch_bounds__(256) void conv1b_dual(
    const float* __restrict__ x_forward, const float* __restrict__ wT1b,
    const float* __restrict__ thr_p, float* __restrict__ outA,
    float* __restrict__ outC) {
  __shared__ float tile[32][6][66];
  const int tid = threadIdx.x;
  const int branch = blockIdx.x >> 9;
  const int bb = blockIdx.x & 511;
  const int tileb = bb & 255;
  const int cbase = (bb >> 8) << 4;
  const int tX = (tileb & 3) << 6;
  const int tY = (tileb >> 2) << 2;
  const float thr = thr_p[0];
  const bool soft = (branch == 0);
  for (int idx = tid; idx < 32 * 396; idx += 256) {
    int ci = idx / 396;
    int r = idx - ci * 396;
    int yy = r / 66;
    int xx = r - yy * 66;
    int gy = tY + yy - 1, gxx = tX + xx - 1;
    float v = 0.0f;
    if (gy >= 0 && gy < 256 && gxx >= 0 && gxx < 256)
      v = x_forward[(ci << 16) + (gy << 8) + gxx];
    if (soft) {
      float av = fabsf(v) - thr;
      v = av > 0.0f ? (v < 0.0f ? -av : av) : 0.0f;
    }
    tile[ci][yy][xx] = v;
  }
  __syncthreads();
  const int px = tid & 63, py = tid >> 6;
  float acc[16];
  #pragma unroll
  for (int i = 0; i < 16; ++i) acc[i] = 0.0f;
  for (int ci = 0; ci < 32; ++ci) {
    float v[9];
    #pragma unroll
    for (int dy = 0; dy < 3; ++dy)
      #pragma unroll
      for (int dx = 0; dx < 3; ++dx)
        v[dy * 3 + dx] = tile[ci][py + dy][px + dx];
    #pragma unroll
    for (int j = 0; j < 9; ++j) {
      const float* wrow = wT1b + (ci * 9 + j) * 32 + cbase;
      #pragma unroll
      for (int co = 0; co < 16; ++co) acc[co] = fmaf(v[j], wrow[co], acc[co]);
    }
  }
  float* outp = soft ? outA : outC;
  const int p = ((tY + py) << 8) + tX + px;
  #pragma unroll
  for (int co = 0; co < 16; ++co)
    outp[((cbase + co) << 16) + p] = fmaxf(acc[co], 0.0f);
}

// ---------------------------------------------------------------------------
// Dual conv2_backward (32 -> 1), LDS-tiled. branch 0: x_pred = conv(bufA);
// branch 1: symloss = conv(bufC) - x_input. grid 512.
// ---------------------------------------------------------------------------
__global__ __launch_bounds__(256) void conv2b_dual(
    const float* __restrict__ bufA, const float* __restrict__ bufC,
    const float* __restrict__ w, const float* __restrict__ x_input,
    float* __restrict__ out) {
  __shared__ float tile[32][6][66];
  const int tid = threadIdx.x;
  const int branch = blockIdx.x >> 8;
  const int tileb = blockIdx.x & 255;
  const int tX = (tileb & 3) << 6;
  const int tY = (tileb >> 2) << 2;
  const float* in = branch ? bufC : bufA;
  for (int idx = tid; idx < 32 * 396; idx += 256) {
    int ci = idx / 396;
    int r = idx - ci * 396;
    int yy = r / 66;
    int xx = r - yy * 66;
    int gy = tY + yy - 1, gxx = tX + xx - 1;
    float v = 0.0f;
    if (gy >= 0 && gy < 256 && gxx >= 0 && gxx < 256)
      v = in[(ci << 16) + (gy << 8) + gxx];
    tile[ci][yy][xx] = v;
  }
  __syncthreads();
  const int px = tid & 63, py = tid >> 6;
  float acc = 0.0f;
  for (int ci = 0; ci < 32; ++ci) {
    #pragma unroll
    for (int dy = 0; dy < 3; ++dy)
      #pragma unroll
      for (int dx = 0; dx < 3; ++dx)
        acc = fmaf(tile[ci][py + dy][px + dx], w[ci * 9 + dy * 3 + dx], acc);
  }
  const int p = ((tY + py) << 8) + tX + px;
  if (branch == 0) out[p] = acc;
  else out[65536 + p] = acc - x_input[p];
}

extern "C" void kernel_launch(void* const* d_in, const int* in_sizes, int n_in,
                              void* d_out, int out_size, void* d_ws, size_t ws_size,
                              hipStream_t stream) {
  const float* x       = (const float*)d_in[0];
  const float* theta   = (const float*)d_in[1];
  const float* sino_in = (const float*)d_in[2];
  const float* lam     = (const float*)d_in[3];
  const float* thr     = (const float*)d_in[4];
  const float* w_c1f   = (const float*)d_in[5];
  const float* w_c2f   = (const float*)d_in[6];
  const float* w_c1b   = (const float*)d_in[7];
  const float* w_c2b   = (const float*)d_in[8];
  float* out = (float*)d_out;
  float* ws  = (float*)d_ws;

  float* h         = ws + H_OFF;
  float* sino_pred = ws + SINO_OFF;
  float* diff      = ws + DIFF_OFF;
  float* x_input   = ws + XIN_OFF;
  float* wT2f      = ws + WT2F_OFF;
  float* wT1b      = ws + WT1B_OFF;
  float* bufA      = ws + BUFA_OFF;
  float* bufB      = ws + BUFB_OFF;
  float* bufC      = ws + BUFC_OFF;
  float4* quadP    = (float4*)(ws + BUFA_OFF);   // dead once fwdproj completes

  setup_kernel<<<909, 256, 0, stream>>>(sino_in, w_c2f, w_c1b, x, h, diff,
                                        wT2f, wT1b, quadP, x_input);
  fwdproj<<<2048, 256, 0, stream>>>(quadP, theta, sino_pred);
  filt<<<256, 256, 0, stream>>>(sino_pred, h, diff);
  backproj_part<<<1024, 256, 0, stream>>>(diff, theta, lam, x_input);
  conv12f<<<256, 256, 0, stream>>>(x_input, w_c1f, wT2f, bufB);
  conv1b_dual<<<1024, 256, 0, stream>>>(bufB, wT1b, thr, bufA, bufC);
  conv2b_dual<<<512, 256, 0, stream>>>(bufA, bufC, w_c2b, x_input, out);
}

// Round 7
// 165.922 us; speedup vs baseline: 1.9501x; 1.6477x over previous
//
#include <hip/hip_runtime.h>

#define DEV_INLINE __device__ __forceinline__

// Problem constants
#define HH 256
#define WW 256
#define AA 64
#define DCC 1024
#define NS 512
#define PI_F 3.14159265358979323846f

// ws layout (float offsets)
#define H_OFF     0          // 2048
#define SINO_OFF  2048       // 65536
#define DIFF_OFF  67584      // 65536
#define XIN_OFF   133120     // 65536
#define WF2F_OFF  198656     // 4608 ints (18 groups x 64 lanes x int4)
#define WF1B_OFF  207872     // 4608 ints
#define BUFA_OFF  217088     // quadP lives here (258*258 float4)
#define BUFB_OFF  2314240    // x_forward (32 planes fp32)

typedef short bf16x8 __attribute__((ext_vector_type(8)));
typedef float f32x4 __attribute__((ext_vector_type(4)));

union FragI4 { int4 i4; bf16x8 v; };
union FragI  { int i[4]; bf16x8 v; };

DEV_INLINE unsigned rne1(float a) {
  unsigned u = __float_as_uint(a);
  return (u + 0x7FFFu + ((u >> 16) & 1u)) >> 16;
}
DEV_INLINE int pack_rne(float a, float b) {
  return (int)(rne1(a) | (rne1(b) << 16));
}

// ---------------------------------------------------------------------------
// Setup: ramp-filter h, diff = -sinogram, MFMA weight frags, quadP, x_input=x.
// h[n] = (1/2048) * [ (-1)^n + (1/512) * sum_{k=1}^{1023} k*cos(pi*k*n/1024) ]
// wfrag layout: int index ((j*2+mt)*64 + L)*4 + d holds bf16 pair for
//   co = mt*16+(L&15), ci = (L>>4)*8 + 2d (+1), tap j.  (A-operand order)
//   Total 18*64*4 = 4608 ints per weight matrix -> 18 blocks each.
// blocks: 0..63 h | 64..319 diff | 320..337 wf2f | 338..355 wf1b |
//         356..616 quadP | 617..872 x_input=x
// ---------------------------------------------------------------------------
__global__ __launch_bounds__(256) void setup_kernel(
    const float* __restrict__ sino_in, const float* __restrict__ w2f,
    const float* __restrict__ w1b, const float* __restrict__ img,
    float* __restrict__ h, float* __restrict__ diff,
    int* __restrict__ wf2f, int* __restrict__ wf1b,
    float4* __restrict__ quadP, float* __restrict__ x_input) {
  const int b = blockIdx.x;
  const int tid = threadIdx.x;
  if (b < 64) {
    __shared__ float hp[8][32];
    const int cell = tid & 31;
    const int kq = tid >> 5;
    const int n = b * 32 + cell;
    float ssum = 0.0f;
    const float ang_scale = PI_F / 1024.0f;
    for (int k = kq * 128; k < kq * 128 + 128; ++k) {
      int m = (k * n) & 2047;             // exact angle reduction mod 2*pi
      ssum += (float)k * __cosf((float)m * ang_scale);
    }
    hp[kq][cell] = ssum;
    __syncthreads();
    if (tid < 32) {
      float S = 0.0f;
      #pragma unroll
      for (int q = 0; q < 8; ++q) S += hp[q][tid];
      int nn = b * 32 + tid;
      float sgn = (nn & 1) ? -1.0f : 1.0f;
      h[nn] = (S * (1.0f / 512.0f) + sgn) * (1.0f / 2048.0f);
    }
  } else if (b < 320) {
    int idx = (b - 64) * 256 + tid;       // < 65536
    diff[idx] = -sino_in[idx];
  } else if (b < 356) {
    const bool second = (b >= 338);
    int idx = (b - (second ? 338 : 320)) * 256 + tid;   // < 4608
    if (idx < 4608) {
      int d = idx & 3;
      int L = (idx >> 2) & 63;
      int jm = idx >> 8;                  // 0..17
      int j = jm >> 1, mt = jm & 1;
      int co = mt * 16 + (L & 15);
      int ci0 = (L >> 4) * 8 + 2 * d;
      const float* w = second ? w1b : w2f;
      int v = pack_rne(w[co * 288 + ci0 * 9 + j], w[co * 288 + (ci0 + 1) * 9 + j]);
      (second ? wf1b : wf2f)[idx] = v;
    }
  } else if (b < 617) {
    int idx = (b - 356) * 256 + tid;
    if (idx < 258 * 258) {
      int y = idx / 258;
      int x = idx - y * 258;
      float4 v;
      int ay = y - 1, bx = x - 1;          // img coords for P(y,x)
      bool y0ok = (ay >= 0 && ay < 256);
      bool y1ok = (ay + 1 >= 0 && ay + 1 < 256);
      bool x0ok = (bx >= 0 && bx < 256);
      bool x1ok = (bx + 1 >= 0 && bx + 1 < 256);
      v.x = (y0ok && x0ok) ? img[(ay << 8) + bx] : 0.0f;
      v.y = (y0ok && x1ok) ? img[(ay << 8) + bx + 1] : 0.0f;
      v.z = (y1ok && x0ok) ? img[((ay + 1) << 8) + bx] : 0.0f;
      v.w = (y1ok && x1ok) ? img[((ay + 1) << 8) + bx + 1] : 0.0f;
      quadP[idx] = v;
    }
  } else {
    int idx = (b - 617) * 256 + tid;      // < 65536
    x_input[idx] = img[idx];
  }
}

// ---------------------------------------------------------------------------
// Fan-beam forward projection (unchanged from passing R5 version).
// ---------------------------------------------------------------------------
__global__ __launch_bounds__(256) void fwdproj(
    const float4* __restrict__ quadP, const float* __restrict__ theta,
    float* __restrict__ sino) {
  __shared__ float part[8][32];
  __shared__ float cs[2];
  const int tid = threadIdx.x;
  const int a = blockIdx.x >> 5;
  const int cell = tid & 31;
  const int chunk = tid >> 5;
  const int d = ((blockIdx.x & 31) << 5) + cell;
  if (tid == 0) {
    float th = theta[a];
    cs[0] = cosf(th);
    cs[1] = sinf(th);
  }
  __syncthreads();
  const float c = cs[0], s = cs[1];
  const float u = ((float)d - 511.5f) * 2.0f;
  const float dxv = -1000.0f * c - u * s;
  const float dyv = -1000.0f * s + u * c;
  const float L = sqrtf(1.0e6f + u * u);
  const float sx = fmaf(500.0f, c, 127.5f);
  const float sy = fmaf(500.0f, s, 127.5f);

  float tlo = 0.0f, thi = 1.0f;
  if (fabsf(dxv) > 1e-6f) {
    float inv = 1.0f / dxv;
    float a0 = (-1.0f - sx) * inv, a1 = (256.0f - sx) * inv;
    tlo = fmaxf(tlo, fminf(a0, a1));
    thi = fminf(thi, fmaxf(a0, a1));
  } else if (sx <= -1.0f || sx >= 256.0f) {
    thi = -1.0f;
  }
  if (fabsf(dyv) > 1e-6f) {
    float inv = 1.0f / dyv;
    float a0 = (-1.0f - sy) * inv, a1 = (256.0f - sy) * inv;
    tlo = fmaxf(tlo, fminf(a0, a1));
    thi = fminf(thi, fmaxf(a0, a1));
  } else if (sy <= -1.0f || sy >= 256.0f) {
    thi = -1.0f;
  }
  int imin = (int)ceilf(tlo * 512.0f - 0.5f) - 1;
  imin = imin < 0 ? 0 : imin;
  int imax = (int)floorf(thi * 512.0f - 0.5f) + 1;
  imax = imax > 511 ? 511 : imax;

  float acc = 0.0f;
  for (int i = imin + chunk; i <= imax; i += 8) {
    float t = ((float)i + 0.5f) * (1.0f / 512.0f);
    float cx = fmaf(t, dxv, sx);
    float cy = fmaf(t, dyv, sy);
    cx = fminf(fmaxf(cx, -1.0f), 256.0f);
    cy = fminf(fmaxf(cy, -1.0f), 256.0f);
    float xf = floorf(cx), yf = floorf(cy);
    float fx = cx - xf, fy = cy - yf;
    int ix = (int)xf + 1;
    int iy = (int)yf + 1;
    float4 q = quadP[iy * 258 + ix];
    float gx = 1.0f - fx, gy = 1.0f - fy;
    acc += gy * (gx * q.x + fx * q.y) + fy * (gx * q.z + fx * q.w);
  }
  part[chunk][cell] = acc;
  __syncthreads();
  if (tid < 32) {
    float r = 0.0f;
    #pragma unroll
    for (int q = 0; q < 8; ++q) r += part[q][tid];
    sino[a * 1024 + ((blockIdx.x & 31) << 5) + tid] = r * (L * (1.0f / 512.0f));
  }
}

// ---------------------------------------------------------------------------
// Ramp filter as direct circular conv, atomicAdd into diff (unchanged).
// ---------------------------------------------------------------------------
__global__ __launch_bounds__(256) void filt(
    const float* __restrict__ sino_pred, const float* __restrict__ h,
    float* __restrict__ diff) {
  __shared__ __align__(16) float srow[256];
  __shared__ __align__(16) float hext[4104];
  const int a = blockIdx.x >> 2;
  const int q = blockIdx.x & 3;
  const int tid = threadIdx.x;
  const int k0base = q * 256;
  srow[tid] = sino_pred[a * 1024 + k0base + tid];
  for (int n = tid; n < 4104; n += 256) hext[n] = h[(n - 2051) & 2047];
  __syncthreads();
  const int dd0 = tid * 4;
  float acc0 = 0.f, acc1 = 0.f, acc2 = 0.f, acc3 = 0.f;
  #pragma unroll 4
  for (int kk = 0; kk < 256; kk += 4) {
    float4 sv = *reinterpret_cast<const float4*>(&srow[kk]);
    int nb = dd0 + 2048 - k0base - kk;
    float4 hA = *reinterpret_cast<const float4*>(&hext[nb]);
    float4 hB = *reinterpret_cast<const float4*>(&hext[nb + 4]);
    acc0 = fmaf(sv.x, hA.w, acc0); acc0 = fmaf(sv.y, hA.z, acc0);
    acc0 = fmaf(sv.z, hA.y, acc0); acc0 = fmaf(sv.w, hA.x, acc0);
    acc1 = fmaf(sv.x, hB.x, acc1); acc1 = fmaf(sv.y, hA.w, acc1);
    acc1 = fmaf(sv.z, hA.z, acc1); acc1 = fmaf(sv.w, hA.y, acc1);
    acc2 = fmaf(sv.x, hB.y, acc2); acc2 = fmaf(sv.y, hB.x, acc2);
    acc2 = fmaf(sv.z, hA.w, acc2); acc2 = fmaf(sv.w, hA.z, acc2);
    acc3 = fmaf(sv.x, hB.z, acc3); acc3 = fmaf(sv.y, hB.y, acc3);
    acc3 = fmaf(sv.z, hB.x, acc3); acc3 = fmaf(sv.w, hA.w, acc3);
  }
  float* o = diff + a * 1024 + dd0;
  atomicAdd(o + 0, acc0);
  atomicAdd(o + 1, acc1);
  atomicAdd(o + 2, acc2);
  atomicAdd(o + 3, acc3);
}

// ---------------------------------------------------------------------------
// Pixel-driven backprojection, angle-split x4 (unchanged).
// ---------------------------------------------------------------------------
__global__ __launch_bounds__(256) void backproj_part(
    const float* __restrict__ diff, const float* __restrict__ theta,
    const float* __restrict__ lam_p, float* __restrict__ x_input) {
  __shared__ float cst[16], snt[16];
  const int tid = threadIdx.x;
  const int tileb = blockIdx.x & 255;
  const int a0 = (blockIdx.x >> 8) << 4;
  if (tid < 16) {
    float th = theta[a0 + tid];
    cst[tid] = cosf(th);
    snt[tid] = sinf(th);
  }
  __syncthreads();
  const int tX = (tileb & 3) << 6;
  const int tY = (tileb >> 2) << 2;
  const int pxi = tX + (tid & 63);
  const int pyi = tY + (tid >> 6);
  const float gx = (float)pxi - 127.5f;
  const float gy = (float)pyi - 127.5f;
  float acc = 0.0f;
  for (int ai = 0; ai < 16; ++ai) {
    float c = cst[ai], s = snt[ai];
    float xr = gx * c + gy * s;
    float yr = gy * c - gx * s;
    float denom = 500.0f - xr;
    float inv = 1.0f / denom;
    float uu = yr * 1000.0f * inv;
    float wgt = 250000.0f * inv * inv;
    float iu = uu * 0.5f + 511.5f;
    float i0f = floorf(iu);
    float fr = iu - i0f;
    int i0 = (int)i0f;
    int c0 = min(max(i0, 0), 1023);
    int c1 = min(max(i0 + 1, 0), 1023);
    float m0 = (i0 >= 0 && i0 < 1024) ? 1.0f : 0.0f;
    float m1 = (i0 + 1 >= 0 && i0 + 1 < 1024) ? 1.0f : 0.0f;
    const float* row = diff + (a0 + ai) * 1024;
    float v0 = row[c0] * m0;
    float v1 = row[c1] * m1;
    acc += (v0 * (1.0f - fr) + v1 * fr) * wgt;
  }
  int p = (pyi << 8) + pxi;
  atomicAdd(x_input + p, -lam_p[0] * 0.04908738521234052f * acc);
}

// ---------------------------------------------------------------------------
// Fused conv1_forward + relu (VALU) + conv2_forward (MFMA bf16).
// Tile 64x4 out px. htile: 66x6 halo px, pixel-major 32ch bf16, 17-dw stride.
// Halo px outside image -> h = 0 (conv2's zero padding).
// MFMA: A = weights (M=co, from wf2f frags), B = activations (N=16 px).
// ---------------------------------------------------------------------------
__global__ __launch_bounds__(256) void conv12f(
    const float* __restrict__ x_input, const float* __restrict__ w1f,
    const int* __restrict__ wf2f, float* __restrict__ x_forward) {
  __shared__ float xin[8][68];
  __shared__ int htile[6732];            // 396 px * 17 dw
  const int tid = threadIdx.x;
  const int lane = tid & 63;
  const int wave = tid >> 6;
  const int tX = (blockIdx.x & 3) << 6;
  const int tY = (blockIdx.x >> 2) << 2;

  // preload weight A-frags (16B each, L2-hot)
  FragI4 wf[2][9];
  const int4* wfg = (const int4*)wf2f;
  #pragma unroll
  for (int mt = 0; mt < 2; ++mt)
    #pragma unroll
    for (int j = 0; j < 9; ++j) wf[mt][j].i4 = wfg[(j * 2 + mt) * 64 + lane];

  for (int idx = tid; idx < 544; idx += 256) {
    int sy = idx / 68;
    int sx = idx - sy * 68;
    int gy = tY + sy - 2, gx = tX + sx - 2;
    xin[sy][sx] = (gy >= 0 && gy < 256 && gx >= 0 && gx < 256)
                      ? x_input[(gy << 8) + gx] : 0.0f;
  }
  __syncthreads();

  // phase 1: h = relu(conv1f(x_input)) on 66x6 halo grid, bf16-packed
  for (int pos = tid; pos < 396; pos += 256) {
    int yy = pos / 66;
    int xx = pos - yy * 66;
    int hy = tY + yy - 1, hx = tX + xx - 1;
    bool hin = (hy >= 0 && hy < 256 && hx >= 0 && hx < 256);
    float v[9];
    #pragma unroll
    for (int dy = 0; dy < 3; ++dy)
      #pragma unroll
      for (int dx = 0; dx < 3; ++dx) v[dy * 3 + dx] = xin[yy + dy][xx + dx];
    #pragma unroll
    for (int c2 = 0; c2 < 16; ++c2) {
      float r0 = 0.0f, r1 = 0.0f;
      #pragma unroll
      for (int j = 0; j < 9; ++j) {
        r0 = fmaf(v[j], w1f[(2 * c2) * 9 + j], r0);
        r1 = fmaf(v[j], w1f[(2 * c2 + 1) * 9 + j], r1);
      }
      r0 = hin ? fmaxf(r0, 0.0f) : 0.0f;
      r1 = hin ? fmaxf(r1, 0.0f) : 0.0f;
      htile[pos * 17 + c2] = pack_rne(r0, r1);
    }
  }
  __syncthreads();

  // phase 2: x_forward = conv2f(h) via MFMA. wave = row y; 4 x-tiles of 16.
  const int y = wave;
  const int n = lane & 15;
  const int q = lane >> 4;
  for (int xt = 0; xt < 4; ++xt) {
    const int x0 = xt << 4;
    #pragma unroll
    for (int mt = 0; mt < 2; ++mt) {
      f32x4 acc = {0.f, 0.f, 0.f, 0.f};
      #pragma unroll
      for (int j = 0; j < 9; ++j) {
        int dy = j / 3, dx = j - dy * 3;
        int pb = (y + dy) * 66 + x0 + dx;
        int base = (pb + n) * 17 + q * 4;
        FragI bf;
        bf.i[0] = htile[base];
        bf.i[1] = htile[base + 1];
        bf.i[2] = htile[base + 2];
        bf.i[3] = htile[base + 3];
        acc = __builtin_amdgcn_mfma_f32_16x16x32_bf16(wf[mt][j].v, bf.v, acc, 0, 0, 0);
      }
      const int gpos = ((tY + y) << 8) + tX + x0 + n;
      #pragma unroll
      for (int r = 0; r < 4; ++r) {
        int co = mt * 16 + q * 4 + r;
        x_forward[(co << 16) + gpos] = acc[r];
      }
    }
  }
}

// ---------------------------------------------------------------------------
// branch_tail: per branch (0: soft(x_forward), 1: x_forward):
//   D1 = relu(conv1b(in)) on the 66x6 halo region via MFMA (bf16),
//   then out = conv2b(D1) (VALU dot from LDS bf16), minus x_input for br 1.
// grid 512 = branch(2) x tile(256). 2 blocks/CU (63.9 KB LDS).
// ---------------------------------------------------------------------------
__global__ __launch_bounds__(256) void branch_tail(
    const float* __restrict__ x_forward, const int* __restrict__ wf1b,
    const float* __restrict__ w2b, const float* __restrict__ thr_p,
    const float* __restrict__ x_input, float* __restrict__ out) {
  __shared__ int ldsX[9248];             // 544 px (68x8 halo2) * 17 dw
  __shared__ short ldsD[13464];          // 396 px (66x6) * 34 bf16
  const int tid = threadIdx.x;
  const int lane = tid & 63;
  const int wave = tid >> 6;
  const int branch = blockIdx.x >> 8;
  const int tileb = blockIdx.x & 255;
  const int tX = (tileb & 3) << 6;
  const int tY = (tileb >> 2) << 2;
  const float thr = thr_p[0];
  const bool soft = (branch == 0);

  // preload weight A-frags
  FragI4 wf[2][9];
  const int4* wfg = (const int4*)wf1b;
  #pragma unroll
  for (int mt = 0; mt < 2; ++mt)
    #pragma unroll
    for (int j = 0; j < 9; ++j) wf[mt][j].i4 = wfg[(j * 2 + mt) * 64 + lane];

  // stage soft(x_forward)/x_forward: 68x8 px x 32 ci -> bf16 pairs
  for (int idx = tid; idx < 8704; idx += 256) {
    int c2 = idx / 544;
    int p = idx - c2 * 544;
    int sy = p / 68;
    int sx = p - sy * 68;
    int gy = tY + sy - 2, gx = tX + sx - 2;
    float v0 = 0.0f, v1 = 0.0f;
    if (gy >= 0 && gy < 256 && gx >= 0 && gx < 256) {
      int g = (gy << 8) + gx;
      v0 = x_forward[((2 * c2) << 16) + g];
      v1 = x_forward[((2 * c2 + 1) << 16) + g];
    }
    if (soft) {
      float a0 = fabsf(v0) - thr;
      v0 = a0 > 0.0f ? (v0 < 0.0f ? -a0 : a0) : 0.0f;
      float a1 = fabsf(v1) - thr;
      v1 = a1 > 0.0f ? (v1 < 0.0f ? -a1 : a1) : 0.0f;
    }
    ldsX[p * 17 + c2] = pack_rne(v0, v1);
  }
  __syncthreads();

  // phase A: D1 = relu(conv1b) over region rx -1..64, ry -1..4 (tiles of 16px)
  const int n = lane & 15;
  const int q = lane >> 4;
  const int rxtab[5] = {-1, 15, 31, 47, 49};
  for (int t = wave; t < 30; t += 4) {
    int trow = t / 5;
    int ry = trow - 1;
    int rx0 = rxtab[t - trow * 5];
    int rxn = rx0 + n;
    bool inimg = ((unsigned)(tX + rxn) < 256u) && ((unsigned)(tY + ry) < 256u);
    int wrbase = ((ry + 1) * 66 + rxn + 1) * 34;
    #pragma unroll
    for (int mt = 0; mt < 2; ++mt) {
      f32x4 acc = {0.f, 0.f, 0.f, 0.f};
      #pragma unroll
      for (int j = 0; j < 9; ++j) {
        int dy = j / 3, dx = j - dy * 3;
        int pb = (ry + 1 + dy) * 68 + rx0 + 1 + dx;
        int base = (pb + n) * 17 + q * 4;
        FragI bf;
        bf.i[0] = ldsX[base];
        bf.i[1] = ldsX[base + 1];
        bf.i[2] = ldsX[base + 2];
        bf.i[3] = ldsX[base + 3];
        acc = __builtin_amdgcn_mfma_f32_16x16x32_bf16(wf[mt][j].v, bf.v, acc, 0, 0, 0);
      }
      #pragma unroll
      for (int r = 0; r < 4; ++r) {
        int co = mt * 16 + q * 4 + r;
        float v = inimg ? fmaxf(acc[r], 0.0f) : 0.0f;
        ldsD[wrbase + co] = (short)rne1(v);
      }
    }
  }
  __syncthreads();

  // phase B: out px = sum_{ci,j} D1[px+off(j)][ci] * w2b[ci][j]
  const int px = tid & 63, py = tid >> 6;
  const int* ldsDi = (const int*)ldsD;
  float acc = 0.0f;
  #pragma unroll
  for (int j = 0; j < 9; ++j) {
    int dy = j / 3, dx = j - dy * 3;
    int rp = (py + dy) * 66 + px + dx;
    int base = rp * 17;
    #pragma unroll
    for (int d = 0; d < 16; ++d) {
      int v = ldsDi[base + d];
      float lo = __uint_as_float(((unsigned)v) << 16);
      float hi = __uint_as_float(((unsigned)v) & 0xFFFF0000u);
      acc = fmaf(lo, w2b[(2 * d) * 9 + j], acc);
      acc = fmaf(hi, w2b[(2 * d + 1) * 9 + j], acc);
    }
  }
  const int p = ((tY + py) << 8) + tX + px;
  if (branch == 0) out[p] = acc;
  else out[65536 + p] = acc - x_input[p];
}

extern "C" void kernel_launch(void* const* d_in, const int* in_sizes, int n_in,
                              void* d_out, int out_size, void* d_ws, size_t ws_size,
                              hipStream_t stream) {
  const float* x       = (const float*)d_in[0];
  const float* theta   = (const float*)d_in[1];
  const float* sino_in = (const float*)d_in[2];
  const float* lam     = (const float*)d_in[3];
  const float* thr     = (const float*)d_in[4];
  const float* w_c1f   = (const float*)d_in[5];
  const float* w_c2f   = (const float*)d_in[6];
  const float* w_c1b   = (const float*)d_in[7];
  const float* w_c2b   = (const float*)d_in[8];
  float* out = (float*)d_out;
  float* ws  = (float*)d_ws;

  float* h         = ws + H_OFF;
  float* sino_pred = ws + SINO_OFF;
  float* diff      = ws + DIFF_OFF;
  float* x_input   = ws + XIN_OFF;
  int*   wf2f      = (int*)(ws + WF2F_OFF);
  int*   wf1b      = (int*)(ws + WF1B_OFF);
  float4* quadP    = (float4*)(ws + BUFA_OFF);   // dead once fwdproj completes
  float* x_forward = ws + BUFB_OFF;

  setup_kernel<<<873, 256, 0, stream>>>(sino_in, w_c2f, w_c1b, x, h, diff,
                                        wf2f, wf1b, quadP, x_input);
  fwdproj<<<2048, 256, 0, stream>>>(quadP, theta, sino_pred);
  filt<<<256, 256, 0, stream>>>(sino_pred, h, diff);
  backproj_part<<<1024, 256, 0, stream>>>(diff, theta, lam, x_input);
  conv12f<<<256, 256, 0, stream>>>(x_input, w_c1f, wf2f, x_forward);
  branch_tail<<<512, 256, 0, stream>>>(x_forward, wf1b, w_c2b, thr, x_input, out);
}